// Round 11
// baseline (169.316 us; speedup 1.0000x reference)
//
#include <hip/hip_runtime.h>
#include <hip/hip_bf16.h>
#include <math.h>
#include <stdint.h>

#define B_SZ   8
#define T_SEQ  2048
#define DIM    256
#define NH     32            // B*E
#define DE     64
#define BAND   509           // |j-i|<=509 can have nonzero f32 punish (denormals)
#define M_ROWS (B_SZ * T_SEQ)

typedef __attribute__((ext_vector_type(8))) short short8;   // 8 bf16 (4 VGPRs)
typedef __attribute__((ext_vector_type(4))) float floatx4;  // MFMA C/D frag
typedef __attribute__((ext_vector_type(4))) unsigned uintx4;
typedef unsigned short ushort_t;

__device__ __forceinline__ ushort_t f2bf(float x) {   // RNE f32->bf16 (scalar)
    unsigned u = __float_as_uint(x);
    u += 0x7fffu + ((u >> 16) & 1u);
    return (ushort_t)(u >> 16);
}
__device__ __forceinline__ float bf2f(ushort_t b) {
    return __uint_as_float(((unsigned)b) << 16);
}
// RNE pack of 2 f32 -> 2 bf16 via the OFFICIAL compiler path (m240: compiler
// emits v_cvt_pk_bf16_f32 for float->bf16 casts; inline-asm variant is BANNED
// -- single-delta R8 proved it produces garbage on this toolchain).
__device__ __forceinline__ unsigned pack2(float a, float b) {
    unsigned lo = __bfloat16_as_ushort(__float2bfloat16(a));
    unsigned hi = __bfloat16_as_ushort(__float2bfloat16(b));
    return lo | (hi << 16);
}

__device__ __forceinline__ double pd_exact(int d, float th) {
    float df  = (float)d;                      // (-d)^2 == d^2 exactly
    float arg = (-(df * df)) / (th * th);      // exact same f32 ops as numpy
    double pdd = exp((double)arg);
    if (pdd < 1.17549435082228751e-38)
        return rint(pdd * 0x1p149) * 0x1p-149; // f32 RNE into denormal range
    return (double)(float)pdd;
}

// ====== prep: x,w -> bf16; SIGNED tables ====================================
// pdfl[i] = pd(i-512) * log2(e)  (i in [0,1024); used for |dd|<=447)
// thrc[i] = thr(|i-768|)         (i in [0,1536); used for |dd| in [321,704])
__global__ __launch_bounds__(256) void prep_kernel(
    const float* __restrict__ x,
    const float* __restrict__ wq, const float* __restrict__ wk,
    const float* __restrict__ wv, const float* __restrict__ wo,
    const float* __restrict__ theta,
    ushort_t* __restrict__ xb, ushort_t* __restrict__ wb,
    float* __restrict__ thr_g, float* __restrict__ pdf_g)
{
    const int bid = blockIdx.x, tid = threadIdx.x;
    if (bid < 2048) {
        size_t i8 = ((size_t)bid * 256 + tid) * 8;
        float4 a = *(const float4*)(x + i8);
        float4 b = *(const float4*)(x + i8 + 4);
        uint4 o;
        o.x = pack2(a.x, a.y); o.y = pack2(a.z, a.w);
        o.z = pack2(b.x, b.y); o.w = pack2(b.z, b.w);
        *(uint4*)(xb + i8) = o;
    } else if (bid < 2176) {
        size_t w8 = ((size_t)(bid - 2048) * 256 + tid) * 8;
        int which = (int)(w8 >> 16);
        const float* src = (which == 0) ? wq : (which == 1) ? wk : (which == 2) ? wv : wo;
        size_t off = w8 & 65535;
        float4 a = *(const float4*)(src + off);
        float4 b = *(const float4*)(src + off + 4);
        uint4 o;
        o.x = pack2(a.x, a.y); o.y = pack2(a.z, a.w);
        o.z = pack2(b.x, b.y); o.w = pack2(b.z, b.w);
        *(uint4*)(wb + w8) = o;
    } else {
        int i = (bid - 2176) * 256 + tid;      // 10 blocks -> i in [0,2560)
        float th = theta[0];
        if (i < 1024) {
            int d = i - 512;
            pdf_g[i] = (float)pd_exact(d, th) * 1.44269504088896340736f;
        }
        if (i < 1536) {
            int d = i - 768;
            int ad = d < 0 ? -d : d;
            if (ad < 321) {
                thr_g[i] = __builtin_inff();   // never consulted
            } else {
                double pdv = pd_exact(ad, th);
                // exclusion: RN32(s*pd)==0  <=>  |s| <= 2^-150/pd
                thr_g[i] = (pdv == 0.0) ? __builtin_inff() : (float)(0x1p-150 / pdv);
            }
        }
    }
}

// ============ QKV projection: MFMA GEMM + transposed coalesced epilogue =====
// head map: h=b*4+d/64, q=(d%64)*32+t/64, e=t%64.  Qh/Kh masked q>=sl -> 0.
__global__ __launch_bounds__(256, 2) void proj_qkv_mfma(
    const ushort_t* __restrict__ xb, const ushort_t* __restrict__ wb,
    const float* __restrict__ bq, const float* __restrict__ bk,
    const float* __restrict__ bv, const int* __restrict__ seq_len,
    ushort_t* __restrict__ Qh, ushort_t* __restrict__ Kh, ushort_t* __restrict__ Vh)
{
    __shared__ __align__(16) ushort_t Ls[4][64][68];   // per-wave [d][t] slab
    const int wave = threadIdx.x >> 6, lane = threadIdx.x & 63;
    const int quad = lane >> 4, l15 = lane & 15;
    const int task = blockIdx.x * 4 + wave;      // 3072 tasks
    const int nt64 = task % 12;
    const int mstrip = task / 12;
    const int mode = nt64 >> 2;                  // 0:Q 1:K 2:V
    const int nloc_base = (nt64 & 3) * 64;       // d within [0,256)
    const ushort_t* Wp = wb + (size_t)mode * 65536;
    const int m0 = mstrip * 64;
    const int bb = m0 >> 11;
    const int th0 = (m0 >> 6) & 31;
    const int sl = seq_len[bb];
    ushort_t* outp = (mode == 0) ? Qh : (mode == 1) ? Kh : Vh;
    const float* bias = (mode == 0) ? bq : (mode == 1) ? bk : bv;
    const int hh = bb * 4 + (nloc_base >> 6);
    const float oscale = (mode == 0) ? 0.022097086912079612f : 1.0f;  // 1/sqrt(2048)

    short8 Bf[4][8];
    #pragma unroll
    for (int nt = 0; nt < 4; ++nt) {
        int nrow = nloc_base + nt * 16 + l15;
        #pragma unroll
        for (int ks = 0; ks < 8; ++ks)
            Bf[nt][ks] = *(const short8*)(Wp + (size_t)nrow * 256 + ks * 32 + quad * 8);
    }
    float bias4[4];
    #pragma unroll
    for (int nt = 0; nt < 4; ++nt) bias4[nt] = bias[nloc_base + nt * 16 + l15];

    short8 Acur[8];
    #pragma unroll
    for (int ks = 0; ks < 8; ++ks)
        Acur[ks] = *(const short8*)(xb + (size_t)(m0 + l15) * 256 + ks * 32 + quad * 8);

    #pragma unroll
    for (int mb = 0; mb < 4; ++mb) {
        const int mb0 = m0 + mb * 16;
        short8 Anext[8];
        if (mb < 3) {
            #pragma unroll
            for (int ks = 0; ks < 8; ++ks)
                Anext[ks] = *(const short8*)(xb + (size_t)(mb0 + 16 + l15) * 256 + ks * 32 + quad * 8);
        }
        floatx4 acc[4];
        #pragma unroll
        for (int nt = 0; nt < 4; ++nt) acc[nt] = (floatx4){0.f, 0.f, 0.f, 0.f};
        #pragma unroll
        for (int ks = 0; ks < 8; ++ks)
            #pragma unroll
            for (int nt = 0; nt < 4; ++nt)
                acc[nt] = __builtin_amdgcn_mfma_f32_16x16x32_bf16(Acur[ks], Bf[nt][ks], acc[nt], 0, 0, 0);
        // stash into wave-private slab, [d][t] layout, packed b64
        #pragma unroll
        for (int nt = 0; nt < 4; ++nt) {
            float v0 = (acc[nt][0] + bias4[nt]) * oscale;
            float v1 = (acc[nt][1] + bias4[nt]) * oscale;
            float v2 = (acc[nt][2] + bias4[nt]) * oscale;
            float v3 = (acc[nt][3] + bias4[nt]) * oscale;
            uint2 pk; pk.x = pack2(v0, v1); pk.y = pack2(v2, v3);
            *(uint2*)&Ls[wave][nt * 16 + l15][mb * 16 + quad * 4] = pk;
        }
        #pragma unroll
        for (int ks = 0; ks < 8; ++ks) Acur[ks] = Anext[ks];
    }

    // coalesced store: row q = dl*32+th0, 128B of e contiguous
    #pragma unroll
    for (int s = 0; s < 16; ++s) {
        int dl = s * 4 + quad;
        int e0 = l15 * 4;
        uint2 pk = *(const uint2*)&Ls[wave][dl][e0];
        int q = dl * 32 + th0;
        if (mode <= 1 && q >= sl) { pk.x = 0u; pk.y = 0u; }
        *(uint2*)(outp + (((size_t)hh * T_SEQ + q) << 6) + e0) = pk;
    }
}

// ====== V transpose (MFMA-k perm) + fused per-head V column sums ============
// phys col c (within each 64-j block) holds
//   j = 32*(c>>5) + 4*((c>>3)&3) + 16*((c>>2)&1) + (c&3)
// meanV fused: identical add ordering to the old meanv_partial kernel.
__global__ __launch_bounds__(256) void vtrans_kernel(const ushort_t* __restrict__ Vh,
                                                     ushort_t* __restrict__ VTp,
                                                     float* __restrict__ mv)
{
    __shared__ ushort_t Vs[256][66];
    __shared__ float red[32][72];
    const int tid = threadIdx.x;
    const int h = blockIdx.x >> 3, chunk = blockIdx.x & 7;
    const ushort_t* src = Vh + ((size_t)(h * T_SEQ + chunk * 256)) * DE;
    float s[8] = {};
    #pragma unroll
    for (int rep = 0; rep < 8; ++rep) {
        int f = rep * 256 + tid;
        int row = f >> 3, c8 = (f & 7) * 8;    // c8 = (tid&7)*8, row = tid>>3 + 32*rep
        uint4 u = *(const uint4*)(src + (size_t)row * DE + c8);
        *(uint4*)&Vs[row][c8] = u;
        const ushort_t* w = (const ushort_t*)&u;
        #pragma unroll
        for (int i = 0; i < 8; ++i) s[i] += bf2f(w[i]);
    }
    {   // partial column sums of this 256-row chunk (same layout as meanv_partial)
        const int r0 = tid >> 3, es = (tid & 7) * 8;
        #pragma unroll
        for (int i = 0; i < 8; ++i) red[r0][es + i] = s[i];
    }
    __syncthreads();
    if (tid < 64) {
        float t = 0.f;
        #pragma unroll
        for (int g = 0; g < 32; ++g) t += red[g][tid];
        atomicAdd(&mv[h * DE + tid], t);
    }
    const int w = tid >> 6, lane = tid & 63;
    const int half = lane >> 5;
    const int c32 = lane & 31;
    const int cbase = c32 * 8;
    const int blk = cbase >> 6;
    const int cin = cbase & 63;
    #pragma unroll
    for (int rr = 0; rr < 8; ++rr) {
        int e = w * 16 + rr * 2 + half;
        ushort_t tmp[8];
        #pragma unroll
        for (int t = 0; t < 8; ++t) {
            int ci = cin + t;
            int j = blk * 64 + 32 * (ci >> 5) + 4 * ((ci >> 3) & 3)
                  + 16 * ((ci >> 2) & 1) + (ci & 3);
            tmp[t] = Vs[j][e];
        }
        *(uint4*)(VTp + ((size_t)(h * DE + e)) * T_SEQ + chunk * 256 + cbase) = *(uint4*)tmp;
    }
}

// ============ banded flash attention: 4-wave q128 (32 q-rows/wave) ==========
// LDS-read-BW fix: each wave owns TWO 16-row q-groups (qg), so one K/V
// ds_read_b128 pair feeds 2x the MFMAs -> per-CU LDS reads halve.
// All layout contracts (swapped QK^T, pack-direct PV A-frag, VTp perm,
// C/D map, l-reduce) unchanged; wave*16 -> wave*32 + qg*16.
__global__ __launch_bounds__(256) void attn_mfma_kernel(
    const ushort_t* __restrict__ Qh, const ushort_t* __restrict__ Kh,
    const ushort_t* __restrict__ VTp, const float* __restrict__ thr_g,
    const float* __restrict__ pdf_g, const float* __restrict__ mvs,
    const int* __restrict__ seq_len, ushort_t* __restrict__ ctxb)
{
    __shared__ ushort_t Ks [2][64][72];   // [buf][j][e]
    __shared__ ushort_t VTs[2][64][72];   // [buf][e][j-perm]
    __shared__ float pdfl[1024];          // pd(d)*log2e, index d+512
    __shared__ float thrc[1536];          // thr(|d|),    index d+768

    const int tid  = threadIdx.x;
    const int wave = tid >> 6;            // 0..3
    const int lane = tid & 63;
    const int quad = lane >> 4;
    const int l15  = lane & 15;
    // XCD swizzle (4 heads/XCD) + strip stagger (bijective, 16 strips of 128 q)
    const int bid   = blockIdx.x;         // 512 blocks
    const int inner = bid >> 3;           // 0..63
    const int g     = inner >> 4;         // 0..3
    const int strip = ((inner & 15) + g * 4) & 15;
    const int h  = (g << 3) | (bid & 7);
    const int q0 = strip * 128;
    const int b  = h >> 2;
    const int sl = seq_len[b];
    const float invT = 1.0f / (float)T_SEQ;
    ushort_t* outbase = ctxb + ((size_t)b * T_SEQ + q0) * DIM + (size_t)(h & 3) * 64;

    if (q0 >= sl) {   // fully masked strip: uniform softmax over all 2048 -> meanV
        #pragma unroll
        for (int nt = 0; nt < 4; ++nt) {
            ushort_t mval = f2bf(mvs[h * DE + l15 + 16 * nt] * invT);
            #pragma unroll
            for (int qg = 0; qg < 2; ++qg)
                #pragma unroll
                for (int r = 0; r < 4; ++r)
                    outbase[(size_t)(wave * 32 + qg * 16 + quad * 4 + r) * DIM + l15 + 16 * nt] = mval;
        }
        return;
    }

    for (int i = tid; i < 1024; i += 256) pdfl[i] = pdf_g[i];
    for (int i = tid; i < 1536; i += 256) thrc[i] = thr_g[i];

    short8 qa[2][2];   // [qg][khalf] B-operand of the swapped QK^T
    #pragma unroll
    for (int qg = 0; qg < 2; ++qg) {
        const ushort_t* qp = Qh + ((size_t)h * T_SEQ + q0 + wave * 32 + qg * 16 + l15) * DE + quad * 8;
        qa[qg][0] = *(const short8*)(qp);
        qa[qg][1] = *(const short8*)(qp + 32);
    }

    float l_acc[2] = {0.f, 0.f};
    floatx4 cacc[2][4];
    #pragma unroll
    for (int qg = 0; qg < 2; ++qg)
        #pragma unroll
        for (int nt = 0; nt < 4; ++nt) cacc[qg][nt] = (floatx4){0.f, 0.f, 0.f, 0.f};

    int jlo = q0 - BAND;       if (jlo < 0) jlo = 0;
    int jhi = q0 + 127 + BAND; if (jhi > sl - 1) jhi = sl - 1;   // j>=sl: all p=0
    const int jt0 = jlo >> 6, jt1 = jhi >> 6;

    // 256-thread staging: 2 uint4/thread per 64x64 subtile (rows kr, kr+32)
    const int kr  = tid >> 3;            // 0..31
    const int kc8 = (tid & 7) * 8;
    const ushort_t* Kbp = Kh + (size_t)h * T_SEQ * DE;
    const ushort_t* Vbp = VTp + (size_t)h * DE * T_SEQ;
    uint4 pA_k0, pA_k1, pA_v0, pA_v1;    // buffer 0 (subtile a)
    uint4 pB_k0, pB_k1, pB_v0, pB_v1;    // buffer 1 (subtile b)
    {
        const int ja = jt0 << 6;
        const int jb = ((jt0 + 1 <= jt1) ? jt0 + 1 : jt1) << 6;  // clamped
        pA_k0 = *(const uint4*)(Kbp + (size_t)(ja + kr) * DE + kc8);
        pA_k1 = *(const uint4*)(Kbp + (size_t)(ja + kr + 32) * DE + kc8);
        pA_v0 = *(const uint4*)(Vbp + (size_t)kr * T_SEQ + ja + kc8);
        pA_v1 = *(const uint4*)(Vbp + (size_t)(kr + 32) * T_SEQ + ja + kc8);
        pB_k0 = *(const uint4*)(Kbp + (size_t)(jb + kr) * DE + kc8);
        pB_k1 = *(const uint4*)(Kbp + (size_t)(jb + kr + 32) * DE + kc8);
        pB_v0 = *(const uint4*)(Vbp + (size_t)kr * T_SEQ + jb + kc8);
        pB_v1 = *(const uint4*)(Vbp + (size_t)(kr + 32) * T_SEQ + jb + kc8);
    }

    const int qrow0 = q0 + wave * 32 + l15;  // qg=0 row; qg=1 adds 16

    // per-64-subtile body: K/V reads hoisted across the two q-groups
    auto subtile = [&](int s, int j0s) {
        floatx4 ST[2][4];
        #pragma unroll
        for (int nt = 0; nt < 4; ++nt) {
            short8 ka0 = *(const short8*)&Ks[s][l15 + 16 * nt][quad * 8];
            short8 ka1 = *(const short8*)&Ks[s][l15 + 16 * nt][32 + quad * 8];
            #pragma unroll
            for (int qg = 0; qg < 2; ++qg) {
                floatx4 z = {0.f, 0.f, 0.f, 0.f};
                z = __builtin_amdgcn_mfma_f32_16x16x32_bf16(ka0, qa[qg][0], z, 0, 0, 0);
                z = __builtin_amdgcn_mfma_f32_16x16x32_bf16(ka1, qa[qg][1], z, 0, 0, 0);
                ST[qg][nt] = z;
            }
        }

        short8 pa[2][2];
        #pragma unroll
        for (int qg = 0; qg < 2; ++qg) {
            // wave-uniform regime split per 16-q-group: dd in [offw-15, offw+63]
            // fast: |dd| <= 398 (pdfl covers +-511); boundary: |dd| >= 321
            const int offw = j0s - q0 - wave * 32 - qg * 16;
            const int db   = j0s + quad * 4 - (qrow0 + qg * 16);
            float p[4][4];
            if (offw > -384 && offw < 336) {
                if (j0s + 63 < sl) {
                    #pragma unroll
                    for (int nt = 0; nt < 4; ++nt)
                        #pragma unroll
                        for (int r = 0; r < 4; ++r)
                            p[nt][r] = __builtin_amdgcn_exp2f(
                                ST[qg][nt][r] * pdfl[db + 512 + nt * 16 + r]);
                } else {
                    #pragma unroll
                    for (int nt = 0; nt < 4; ++nt)
                        #pragma unroll
                        for (int r = 0; r < 4; ++r) {
                            float v = __builtin_amdgcn_exp2f(
                                ST[qg][nt][r] * pdfl[db + 512 + nt * 16 + r]);
                            p[nt][r] = (j0s + nt * 16 + quad * 4 + r < sl) ? v : 0.f;
                        }
                }
            } else {
                // BOUNDARY: |dd|>=321 -> exp(av)==1.0f exactly; p = incl? 1:0
                // masked j has S==0 exactly -> p=0; |dd|>509 -> thr=inf -> p=0
                #pragma unroll
                for (int nt = 0; nt < 4; ++nt)
                    #pragma unroll
                    for (int r = 0; r < 4; ++r)
                        p[nt][r] = (fabsf(ST[qg][nt][r]) > thrc[db + 768 + nt * 16 + r])
                                   ? 1.0f : 0.0f;
            }

            #pragma unroll
            for (int nt = 0; nt < 4; ++nt)
                l_acc[qg] += (p[nt][0] + p[nt][1]) + (p[nt][2] + p[nt][3]);

            // pack P straight into the PV A-frag: slot k = quad*8+t holds
            // j = 16*(t>>2) + 4*quad + (t&3) (+32 for pa[.][1]) -- matches VTp
            uintx4 t0, t1;
            t0.x = pack2(p[0][0], p[0][1]); t0.y = pack2(p[0][2], p[0][3]);
            t0.z = pack2(p[1][0], p[1][1]); t0.w = pack2(p[1][2], p[1][3]);
            t1.x = pack2(p[2][0], p[2][1]); t1.y = pack2(p[2][2], p[2][3]);
            t1.z = pack2(p[3][0], p[3][1]); t1.w = pack2(p[3][2], p[3][3]);
            pa[qg][0] = __builtin_bit_cast(short8, t0);
            pa[qg][1] = __builtin_bit_cast(short8, t1);
        }

        #pragma unroll
        for (int nt = 0; nt < 4; ++nt) {   // PV; V reads hoisted across qg
            short8 vb0 = *(const short8*)&VTs[s][l15 + 16 * nt][quad * 8];
            short8 vb1 = *(const short8*)&VTs[s][l15 + 16 * nt][32 + quad * 8];
            #pragma unroll
            for (int qg = 0; qg < 2; ++qg) {
                floatx4 c = cacc[qg][nt];
                c = __builtin_amdgcn_mfma_f32_16x16x32_bf16(pa[qg][0], vb0, c, 0, 0, 0);
                c = __builtin_amdgcn_mfma_f32_16x16x32_bf16(pa[qg][1], vb1, c, 0, 0, 0);
                cacc[qg][nt] = c;
            }
        }
    };

    for (int jt = jt0; jt <= jt1; jt += 2) {
        const int j0a = jt << 6;
        const bool has_b = (jt + 1 <= jt1);
        const int j0b = (has_b ? jt + 1 : jt1) << 6;
        __syncthreads();                        // prev reads done before overwrite
        *(uint4*)&Ks [0][kr][kc8]      = pA_k0;
        *(uint4*)&Ks [0][kr + 32][kc8] = pA_k1;
        *(uint4*)&VTs[0][kr][kc8]      = pA_v0;
        *(uint4*)&VTs[0][kr + 32][kc8] = pA_v1;
        *(uint4*)&Ks [1][kr][kc8]      = pB_k0;
        *(uint4*)&Ks [1][kr + 32][kc8] = pB_k1;
        *(uint4*)&VTs[1][kr][kc8]      = pB_v0;
        *(uint4*)&VTs[1][kr + 32][kc8] = pB_v1;
        __syncthreads();
        if (jt + 2 <= jt1) {                    // next pair's loads fly now
            const int jn0 = (jt + 2) << 6;
            const int jn1 = ((jt + 3 <= jt1) ? jt + 3 : jt1) << 6;
            pA_k0 = *(const uint4*)(Kbp + (size_t)(jn0 + kr) * DE + kc8);
            pA_k1 = *(const uint4*)(Kbp + (size_t)(jn0 + kr + 32) * DE + kc8);
            pA_v0 = *(const uint4*)(Vbp + (size_t)kr * T_SEQ + jn0 + kc8);
            pA_v1 = *(const uint4*)(Vbp + (size_t)(kr + 32) * T_SEQ + jn0 + kc8);
            pB_k0 = *(const uint4*)(Kbp + (size_t)(jn1 + kr) * DE + kc8);
            pB_k1 = *(const uint4*)(Kbp + (size_t)(jn1 + kr + 32) * DE + kc8);
            pB_v0 = *(const uint4*)(Vbp + (size_t)kr * T_SEQ + jn1 + kc8);
            pB_v1 = *(const uint4*)(Vbp + (size_t)(kr + 32) * T_SEQ + jn1 + kc8);
        }
        subtile(0, j0a);
        if (has_b) subtile(1, j0b);
    }

    // per qg: l lives per-lane for q = base+l15; quads hold disjoint j-subsets
    #pragma unroll
    for (int qg = 0; qg < 2; ++qg) {
        float lv = l_acc[qg];
        lv += __shfl_xor(lv, 16);
        lv += __shfl_xor(lv, 32);
        const float linv = 1.0f / lv;
        float linv4[4];
        #pragma unroll
        for (int r = 0; r < 4; ++r) linv4[r] = __shfl(linv, quad * 4 + r);

        #pragma unroll
        for (int nt = 0; nt < 4; ++nt) {
            #pragma unroll
            for (int r = 0; r < 4; ++r) {
                int row = wave * 32 + qg * 16 + quad * 4 + r;
                int qgl = q0 + row;
                float o = cacc[qg][nt][r] * linv4[r];
                if (qgl >= sl) o = mvs[h * DE + l15 + 16 * nt] * invT;
                outbase[(size_t)row * DIM + l15 + 16 * nt] = f2bf(o);
            }
        }
    }
}

// ============ output projection + bias + residual (LDS-staged A) ============
__global__ __launch_bounds__(256, 2) void proj_o_mfma(
    const ushort_t* __restrict__ ctx, const ushort_t* __restrict__ wb,
    const float* __restrict__ bo, const float* __restrict__ x,
    float* __restrict__ out)
{
    __shared__ __align__(16) ushort_t As[32][264];
    const int tid = threadIdx.x;
    const int wave = tid >> 6, lane = tid & 63;
    const int quad = lane >> 4, l15 = lane & 15;
    const int m0 = blockIdx.x * 32;
    const int n0 = wave * 64;
    const ushort_t* Wp = wb + (size_t)3 * 65536; // wo

    #pragma unroll
    for (int rep = 0; rep < 4; ++rep) {
        int f = rep * 256 + tid;             // 1024 uint4 = 32x256 bf16
        int row = f >> 5, c8 = (f & 31) * 8;
        *(uint4*)&As[row][c8] = *(const uint4*)(ctx + (size_t)(m0 + row) * 256 + c8);
    }

    short8 Bf[4][8];
    #pragma unroll
    for (int nt = 0; nt < 4; ++nt) {
        int nrow = n0 + nt * 16 + l15;
        #pragma unroll
        for (int ks = 0; ks < 8; ++ks)
            Bf[nt][ks] = *(const short8*)(Wp + (size_t)nrow * 256 + ks * 32 + quad * 8);
    }
    float bias4[4];
    #pragma unroll
    for (int nt = 0; nt < 4; ++nt) bias4[nt] = bo[n0 + nt * 16 + l15];

    __syncthreads();

    #pragma unroll
    for (int mb = 0; mb < 2; ++mb) {
        short8 Af[8];
        #pragma unroll
        for (int ks = 0; ks < 8; ++ks)
            Af[ks] = *(const short8*)&As[mb * 16 + l15][ks * 32 + quad * 8];
        floatx4 acc[4];
        #pragma unroll
        for (int nt = 0; nt < 4; ++nt) acc[nt] = (floatx4){0.f, 0.f, 0.f, 0.f};
        #pragma unroll
        for (int ks = 0; ks < 8; ++ks)
            #pragma unroll
            for (int nt = 0; nt < 4; ++nt)
                acc[nt] = __builtin_amdgcn_mfma_f32_16x16x32_bf16(Af[ks], Bf[nt][ks], acc[nt], 0, 0, 0);
        #pragma unroll
        for (int nt = 0; nt < 4; ++nt) {
            int d = n0 + nt * 16 + l15;
            #pragma unroll
            for (int r = 0; r < 4; ++r) {
                size_t mi = (size_t)(m0 + mb * 16 + quad * 4 + r) * 256 + d;
                out[mi] = acc[nt][r] + bias4[nt] + x[mi];
            }
        }
    }
}

extern "C" void kernel_launch(void* const* d_in, const int* in_sizes, int n_in,
                              void* d_out, int out_size, void* d_ws, size_t ws_size,
                              hipStream_t stream)
{
    (void)in_sizes; (void)n_in; (void)out_size; (void)ws_size;
    const float* x  = (const float*)d_in[0];
    const int*   sl = (const int*)d_in[1];
    const float* wq = (const float*)d_in[2];
    const float* bq = (const float*)d_in[3];
    const float* wk = (const float*)d_in[4];
    const float* bk = (const float*)d_in[5];
    const float* wv = (const float*)d_in[6];
    const float* bv = (const float*)d_in[7];
    const float* wo = (const float*)d_in[8];
    const float* bo = (const float*)d_in[9];
    const float* th = (const float*)d_in[10];
    float* out = (float*)d_out;

    char* ws = (char*)d_ws;
    const size_t SZH = (size_t)M_ROWS * DIM * sizeof(ushort_t);  // 8 MiB
    ushort_t* xb  = (ushort_t*)(ws);
    ushort_t* wb  = (ushort_t*)(ws + SZH);                       // 512 KiB
    ushort_t* Qh  = (ushort_t*)(ws + SZH + 524288);
    ushort_t* Kh  = (ushort_t*)(ws + 2*SZH + 524288);
    ushort_t* Vh  = (ushort_t*)(ws + 3*SZH + 524288);
    ushort_t* VTp = (ushort_t*)(ws + 4*SZH + 524288);
    ushort_t* Cb  = (ushort_t*)(ws + 5*SZH + 524288);
    float*    Mv  = (float*)   (ws + 6*SZH + 524288);            // 8 KiB
    float*    Thr = (float*)   (ws + 6*SZH + 524288 + 8192);     // 6 KiB (1536 f32)
    float*    Pdf = (float*)   (ws + 6*SZH + 524288 + 8192 + 6144); // 4 KiB (1024 f32)

    hipMemsetAsync(Mv, 0, NH * DE * sizeof(float), stream);
    prep_kernel<<<dim3(2186), dim3(256), 0, stream>>>(x, wq, wk, wv, wo, th, xb, wb, Thr, Pdf);
    proj_qkv_mfma<<<dim3(768), dim3(256), 0, stream>>>(xb, wb, bq, bk, bv, sl, Qh, Kh, Vh);
    vtrans_kernel<<<dim3(NH * 8), dim3(256), 0, stream>>>(Vh, VTp, Mv);
    attn_mfma_kernel<<<dim3(512), dim3(256), 0, stream>>>(Qh, Kh, VTp, Thr, Pdf, Mv, sl, Cb);
    proj_o_mfma<<<dim3(512), dim3(256), 0, stream>>>(Cb, wb, bo, x, out);
}

// Round 12
// 157.531 us; speedup vs baseline: 1.0748x; 1.0748x over previous
//
#include <hip/hip_runtime.h>
#include <hip/hip_bf16.h>
#include <math.h>
#include <stdint.h>

#define B_SZ   8
#define T_SEQ  2048
#define DIM    256
#define NH     32            // B*E
#define DE     64
#define BAND   509           // |j-i|<=509 can have nonzero f32 punish (denormals)
#define M_ROWS (B_SZ * T_SEQ)

typedef __attribute__((ext_vector_type(8))) short short8;   // 8 bf16 (4 VGPRs)
typedef __attribute__((ext_vector_type(4))) float floatx4;  // MFMA C/D frag
typedef __attribute__((ext_vector_type(4))) unsigned uintx4;
typedef unsigned short ushort_t;

__device__ __forceinline__ ushort_t f2bf(float x) {   // RNE f32->bf16 (scalar)
    unsigned u = __float_as_uint(x);
    u += 0x7fffu + ((u >> 16) & 1u);
    return (ushort_t)(u >> 16);
}
__device__ __forceinline__ float bf2f(ushort_t b) {
    return __uint_as_float(((unsigned)b) << 16);
}
// RNE pack of 2 f32 -> 2 bf16 via the OFFICIAL compiler path (m240: compiler
// emits v_cvt_pk_bf16_f32 for float->bf16 casts; inline-asm variant is BANNED
// -- single-delta R8 proved it produces garbage on this toolchain).
__device__ __forceinline__ unsigned pack2(float a, float b) {
    unsigned lo = __bfloat16_as_ushort(__float2bfloat16(a));
    unsigned hi = __bfloat16_as_ushort(__float2bfloat16(b));
    return lo | (hi << 16);
}

__device__ __forceinline__ double pd_exact(int d, float th) {
    float df  = (float)d;                      // (-d)^2 == d^2 exactly
    float arg = (-(df * df)) / (th * th);      // exact same f32 ops as numpy
    double pdd = exp((double)arg);
    if (pdd < 1.17549435082228751e-38)
        return rint(pdd * 0x1p149) * 0x1p-149; // f32 RNE into denormal range
    return (double)(float)pdd;
}

// ====== prep: x,w -> bf16; SIGNED tables ====================================
// pdfl[i] = pd(i-512) * log2(e)  (i in [0,1024); used for |dd|<=447)
// thrc[i] = thr(|i-768|)         (i in [0,1536); used for |dd| in [321,704])
__global__ __launch_bounds__(256) void prep_kernel(
    const float* __restrict__ x,
    const float* __restrict__ wq, const float* __restrict__ wk,
    const float* __restrict__ wv, const float* __restrict__ wo,
    const float* __restrict__ theta,
    ushort_t* __restrict__ xb, ushort_t* __restrict__ wb,
    float* __restrict__ thr_g, float* __restrict__ pdf_g)
{
    const int bid = blockIdx.x, tid = threadIdx.x;
    if (bid < 2048) {
        size_t i8 = ((size_t)bid * 256 + tid) * 8;
        float4 a = *(const float4*)(x + i8);
        float4 b = *(const float4*)(x + i8 + 4);
        uint4 o;
        o.x = pack2(a.x, a.y); o.y = pack2(a.z, a.w);
        o.z = pack2(b.x, b.y); o.w = pack2(b.z, b.w);
        *(uint4*)(xb + i8) = o;
    } else if (bid < 2176) {
        size_t w8 = ((size_t)(bid - 2048) * 256 + tid) * 8;
        int which = (int)(w8 >> 16);
        const float* src = (which == 0) ? wq : (which == 1) ? wk : (which == 2) ? wv : wo;
        size_t off = w8 & 65535;
        float4 a = *(const float4*)(src + off);
        float4 b = *(const float4*)(src + off + 4);
        uint4 o;
        o.x = pack2(a.x, a.y); o.y = pack2(a.z, a.w);
        o.z = pack2(b.x, b.y); o.w = pack2(b.z, b.w);
        *(uint4*)(wb + w8) = o;
    } else {
        int i = (bid - 2176) * 256 + tid;      // 10 blocks -> i in [0,2560)
        float th = theta[0];
        if (i < 1024) {
            int d = i - 512;
            pdf_g[i] = (float)pd_exact(d, th) * 1.44269504088896340736f;
        }
        if (i < 1536) {
            int d = i - 768;
            int ad = d < 0 ? -d : d;
            if (ad < 321) {
                thr_g[i] = __builtin_inff();   // never consulted
            } else {
                double pdv = pd_exact(ad, th);
                // exclusion: RN32(s*pd)==0  <=>  |s| <= 2^-150/pd
                thr_g[i] = (pdv == 0.0) ? __builtin_inff() : (float)(0x1p-150 / pdv);
            }
        }
    }
}

// ============ QKV projection: MFMA GEMM, LDS-staged A (read xb 3x not 12x) ==
// 12 % 4 == 0 -> each block's 4 waves share one mstrip, so the 64x256 A-strip
// is staged once per block (proj_o-proven pattern, [.][264] pad = 2-way-free).
// head map: h=b*4+d/64, q=(d%64)*32+t/64, e=t%64.  Qh/Kh masked q>=sl -> 0.
__global__ __launch_bounds__(256, 2) void proj_qkv_mfma(
    const ushort_t* __restrict__ xb, const ushort_t* __restrict__ wb,
    const float* __restrict__ bq, const float* __restrict__ bk,
    const float* __restrict__ bv, const int* __restrict__ seq_len,
    ushort_t* __restrict__ Qh, ushort_t* __restrict__ Kh, ushort_t* __restrict__ Vh)
{
    __shared__ __align__(16) ushort_t As[64][264];     // block-shared A strip
    __shared__ __align__(16) ushort_t Ls[4][64][68];   // per-wave [d][t] slab
    const int tid = threadIdx.x;
    const int wave = tid >> 6, lane = tid & 63;
    const int quad = lane >> 4, l15 = lane & 15;
    const int task = blockIdx.x * 4 + wave;      // 3072 tasks
    const int nt64 = task % 12;
    const int mstrip = task / 12;                // block-uniform (12%4==0)
    const int mode = nt64 >> 2;                  // 0:Q 1:K 2:V
    const int nloc_base = (nt64 & 3) * 64;       // d within [0,256)
    const ushort_t* Wp = wb + (size_t)mode * 65536;
    const int m0 = mstrip * 64;
    const int bb = m0 >> 11;
    const int th0 = (m0 >> 6) & 31;
    const int sl = seq_len[bb];
    ushort_t* outp = (mode == 0) ? Qh : (mode == 1) ? Kh : Vh;
    const float* bias = (mode == 0) ? bq : (mode == 1) ? bk : bv;
    const int hh = bb * 4 + (nloc_base >> 6);
    const float oscale = (mode == 0) ? 0.022097086912079612f : 1.0f;  // 1/sqrt(2048)

    // stage the block's A-strip: 64 rows x 256 cols bf16 = 2048 uint4
    #pragma unroll
    for (int rep = 0; rep < 8; ++rep) {
        int f = rep * 256 + tid;
        int row = f >> 5, c8 = (f & 31) * 8;
        *(uint4*)&As[row][c8] = *(const uint4*)(xb + (size_t)(m0 + row) * 256 + c8);
    }

    short8 Bf[4][8];
    #pragma unroll
    for (int nt = 0; nt < 4; ++nt) {
        int nrow = nloc_base + nt * 16 + l15;
        #pragma unroll
        for (int ks = 0; ks < 8; ++ks)
            Bf[nt][ks] = *(const short8*)(Wp + (size_t)nrow * 256 + ks * 32 + quad * 8);
    }
    float bias4[4];
    #pragma unroll
    for (int nt = 0; nt < 4; ++nt) bias4[nt] = bias[nloc_base + nt * 16 + l15];

    __syncthreads();

    #pragma unroll
    for (int mb = 0; mb < 4; ++mb) {
        short8 Af[8];
        #pragma unroll
        for (int ks = 0; ks < 8; ++ks)
            Af[ks] = *(const short8*)&As[mb * 16 + l15][ks * 32 + quad * 8];
        floatx4 acc[4];
        #pragma unroll
        for (int nt = 0; nt < 4; ++nt) acc[nt] = (floatx4){0.f, 0.f, 0.f, 0.f};
        #pragma unroll
        for (int ks = 0; ks < 8; ++ks)
            #pragma unroll
            for (int nt = 0; nt < 4; ++nt)
                acc[nt] = __builtin_amdgcn_mfma_f32_16x16x32_bf16(Af[ks], Bf[nt][ks], acc[nt], 0, 0, 0);
        // stash into wave-private slab, [d][t] layout, packed b64
        #pragma unroll
        for (int nt = 0; nt < 4; ++nt) {
            float v0 = (acc[nt][0] + bias4[nt]) * oscale;
            float v1 = (acc[nt][1] + bias4[nt]) * oscale;
            float v2 = (acc[nt][2] + bias4[nt]) * oscale;
            float v3 = (acc[nt][3] + bias4[nt]) * oscale;
            uint2 pk; pk.x = pack2(v0, v1); pk.y = pack2(v2, v3);
            *(uint2*)&Ls[wave][nt * 16 + l15][mb * 16 + quad * 4] = pk;
        }
    }

    // coalesced store: row q = dl*32+th0, 128B of e contiguous
    #pragma unroll
    for (int s = 0; s < 16; ++s) {
        int dl = s * 4 + quad;
        int e0 = l15 * 4;
        uint2 pk = *(const uint2*)&Ls[wave][dl][e0];
        int q = dl * 32 + th0;
        if (mode <= 1 && q >= sl) { pk.x = 0u; pk.y = 0u; }
        *(uint2*)(outp + (((size_t)hh * T_SEQ + q) << 6) + e0) = pk;
    }
}

// ====== V transpose (MFMA-k perm) + fused per-head V column sums ============
// phys col c (within each 64-j block) holds
//   j = 32*(c>>5) + 4*((c>>3)&3) + 16*((c>>2)&1) + (c&3)
// meanV fused: identical add ordering to the old meanv_partial kernel.
__global__ __launch_bounds__(256) void vtrans_kernel(const ushort_t* __restrict__ Vh,
                                                     ushort_t* __restrict__ VTp,
                                                     float* __restrict__ mv)
{
    __shared__ ushort_t Vs[256][66];
    __shared__ float red[32][72];
    const int tid = threadIdx.x;
    const int h = blockIdx.x >> 3, chunk = blockIdx.x & 7;
    const ushort_t* src = Vh + ((size_t)(h * T_SEQ + chunk * 256)) * DE;
    float s[8] = {};
    #pragma unroll
    for (int rep = 0; rep < 8; ++rep) {
        int f = rep * 256 + tid;
        int row = f >> 3, c8 = (f & 7) * 8;    // c8 = (tid&7)*8, row = tid>>3 + 32*rep
        uint4 u = *(const uint4*)(src + (size_t)row * DE + c8);
        *(uint4*)&Vs[row][c8] = u;
        const ushort_t* w = (const ushort_t*)&u;
        #pragma unroll
        for (int i = 0; i < 8; ++i) s[i] += bf2f(w[i]);
    }
    {   // partial column sums of this 256-row chunk (same layout as meanv_partial)
        const int r0 = tid >> 3, es = (tid & 7) * 8;
        #pragma unroll
        for (int i = 0; i < 8; ++i) red[r0][es + i] = s[i];
    }
    __syncthreads();
    if (tid < 64) {
        float t = 0.f;
        #pragma unroll
        for (int g = 0; g < 32; ++g) t += red[g][tid];
        atomicAdd(&mv[h * DE + tid], t);
    }
    const int w = tid >> 6, lane = tid & 63;
    const int half = lane >> 5;
    const int c32 = lane & 31;
    const int cbase = c32 * 8;
    const int blk = cbase >> 6;
    const int cin = cbase & 63;
    #pragma unroll
    for (int rr = 0; rr < 8; ++rr) {
        int e = w * 16 + rr * 2 + half;
        ushort_t tmp[8];
        #pragma unroll
        for (int t = 0; t < 8; ++t) {
            int ci = cin + t;
            int j = blk * 64 + 32 * (ci >> 5) + 4 * ((ci >> 3) & 3)
                  + 16 * ((ci >> 2) & 1) + (ci & 3);
            tmp[t] = Vs[j][e];
        }
        *(uint4*)(VTp + ((size_t)(h * DE + e)) * T_SEQ + chunk * 256 + cbase) = *(uint4*)tmp;
    }
}

// ============ banded flash attention: 8-wave q128, j128 double-buffer =======
// (R10-verified 163.9us version, reverted after R11's 2-qg regression:
//  LDS-BW relief bought with occupancy loss is net-negative here.)
__global__ __launch_bounds__(512) void attn_mfma_kernel(
    const ushort_t* __restrict__ Qh, const ushort_t* __restrict__ Kh,
    const ushort_t* __restrict__ VTp, const float* __restrict__ thr_g,
    const float* __restrict__ pdf_g, const float* __restrict__ mvs,
    const int* __restrict__ seq_len, ushort_t* __restrict__ ctxb)
{
    __shared__ ushort_t Ks [2][64][72];   // [buf][j][e]
    __shared__ ushort_t VTs[2][64][72];   // [buf][e][j-perm]
    __shared__ float pdfl[1024];          // pd(d)*log2e, index d+512
    __shared__ float thrc[1536];          // thr(|d|),    index d+768

    const int tid  = threadIdx.x;
    const int wave = tid >> 6;            // 0..7
    const int lane = tid & 63;
    const int quad = lane >> 4;
    const int l15  = lane & 15;
    // XCD swizzle (4 heads/XCD) + strip stagger (bijective, 16 strips of 128 q)
    const int bid   = blockIdx.x;         // 512 blocks
    const int inner = bid >> 3;           // 0..63
    const int g     = inner >> 4;         // 0..3
    const int strip = ((inner & 15) + g * 4) & 15;
    const int h  = (g << 3) | (bid & 7);
    const int q0 = strip * 128;
    const int b  = h >> 2;
    const int sl = seq_len[b];
    const float invT = 1.0f / (float)T_SEQ;
    ushort_t* outbase = ctxb + ((size_t)b * T_SEQ + q0) * DIM + (size_t)(h & 3) * 64;

    if (q0 >= sl) {   // fully masked strip: uniform softmax over all 2048 -> meanV
        #pragma unroll
        for (int nt = 0; nt < 4; ++nt) {
            ushort_t mval = f2bf(mvs[h * DE + l15 + 16 * nt] * invT);
            #pragma unroll
            for (int r = 0; r < 4; ++r)
                outbase[(size_t)(wave * 16 + quad * 4 + r) * DIM + l15 + 16 * nt] = mval;
        }
        return;
    }

    for (int i = tid; i < 1024; i += 512) pdfl[i] = pdf_g[i];
    for (int i = tid; i < 1536; i += 512) thrc[i] = thr_g[i];

    short8 qa0, qa1;   // B-operand of the swapped QK^T (n = l15 -> q row)
    {
        const ushort_t* qp = Qh + ((size_t)h * T_SEQ + q0 + wave * 16 + l15) * DE + quad * 8;
        qa0 = *(const short8*)(qp);
        qa1 = *(const short8*)(qp + 32);
    }

    float l_acc = 0.f;           // this lane's q-row denominator partial
    floatx4 cacc[4];
    #pragma unroll
    for (int nt = 0; nt < 4; ++nt) cacc[nt] = (floatx4){0.f, 0.f, 0.f, 0.f};

    int jlo = q0 - BAND;       if (jlo < 0) jlo = 0;
    int jhi = q0 + 127 + BAND; if (jhi > sl - 1) jhi = sl - 1;   // j>=sl: all p=0
    const int jt0 = jlo >> 6, jt1 = jhi >> 6;

    // 512-thread staging: one uint4 per thread covers a full 64x64 subtile
    const int krow = tid >> 3;           // 0..63
    const int kc8  = (tid & 7) * 8;
    const ushort_t* Kbp = Kh + (size_t)h * T_SEQ * DE;
    const ushort_t* Vbp = VTp + (size_t)h * DE * T_SEQ;
    uint4 kpre0, kpre1, vpre0, vpre1;
    {
        const int ja = jt0 << 6;
        const int jb = ((jt0 + 1 <= jt1) ? jt0 + 1 : jt1) << 6;  // clamped
        kpre0 = *(const uint4*)(Kbp + (size_t)(ja + krow) * DE + kc8);
        vpre0 = *(const uint4*)(Vbp + (size_t)krow * T_SEQ + ja + kc8);
        kpre1 = *(const uint4*)(Kbp + (size_t)(jb + krow) * DE + kc8);
        vpre1 = *(const uint4*)(Vbp + (size_t)krow * T_SEQ + jb + kc8);
    }

    const int qrow = q0 + wave * 16 + l15;   // this lane's q (col of ST)

    // per-64-subtile body, parameterized by LDS buffer + j0s
    auto subtile = [&](int s, int j0s) {
        floatx4 ST[4];
        #pragma unroll
        for (int nt = 0; nt < 4; ++nt) {
            short8 ka0 = *(const short8*)&Ks[s][l15 + 16 * nt][quad * 8];
            short8 ka1 = *(const short8*)&Ks[s][l15 + 16 * nt][32 + quad * 8];
            floatx4 z = {0.f, 0.f, 0.f, 0.f};
            z = __builtin_amdgcn_mfma_f32_16x16x32_bf16(ka0, qa0, z, 0, 0, 0);
            z = __builtin_amdgcn_mfma_f32_16x16x32_bf16(ka1, qa1, z, 0, 0, 0);
            ST[nt] = z;
        }

        // wave-uniform regime split: dd = db + nt*16 + r, dd in [offw-15,offw+63]
        // fast branch: |dd| <= 398 (pdfl covers +-511); boundary: |dd| >= 321
        const int offw = j0s - q0 - wave * 16;
        const int db   = j0s + quad * 4 - qrow;
        float p[4][4];
        if (offw > -384 && offw < 336) {
            if (j0s + 63 < sl) {
                #pragma unroll
                for (int nt = 0; nt < 4; ++nt)
                    #pragma unroll
                    for (int r = 0; r < 4; ++r)
                        p[nt][r] = __builtin_amdgcn_exp2f(
                            ST[nt][r] * pdfl[db + 512 + nt * 16 + r]);
            } else {
                #pragma unroll
                for (int nt = 0; nt < 4; ++nt)
                    #pragma unroll
                    for (int r = 0; r < 4; ++r) {
                        float v = __builtin_amdgcn_exp2f(
                            ST[nt][r] * pdfl[db + 512 + nt * 16 + r]);
                        p[nt][r] = (j0s + nt * 16 + quad * 4 + r < sl) ? v : 0.f;
                    }
            }
        } else {
            // BOUNDARY: |dd|>=321 -> exp(av)==1.0f exactly; p = incl? 1:0
            // masked j has S==0 exactly -> p=0; |dd|>509 -> thr=inf -> p=0
            #pragma unroll
            for (int nt = 0; nt < 4; ++nt)
                #pragma unroll
                for (int r = 0; r < 4; ++r)
                    p[nt][r] = (fabsf(ST[nt][r]) > thrc[db + 768 + nt * 16 + r])
                               ? 1.0f : 0.0f;
        }

        #pragma unroll
        for (int nt = 0; nt < 4; ++nt)
            l_acc += (p[nt][0] + p[nt][1]) + (p[nt][2] + p[nt][3]);

        // pack P straight into the PV A-frag: slot k = quad*8+t holds
        // j = 16*(t>>2) + 4*quad + (t&3) (+32 for pa1) -- matches VTp's perm
        uintx4 t0, t1;
        t0.x = pack2(p[0][0], p[0][1]); t0.y = pack2(p[0][2], p[0][3]);
        t0.z = pack2(p[1][0], p[1][1]); t0.w = pack2(p[1][2], p[1][3]);
        t1.x = pack2(p[2][0], p[2][1]); t1.y = pack2(p[2][2], p[2][3]);
        t1.z = pack2(p[3][0], p[3][1]); t1.w = pack2(p[3][2], p[3][3]);
        short8 pa0 = __builtin_bit_cast(short8, t0);
        short8 pa1 = __builtin_bit_cast(short8, t1);

        #pragma unroll
        for (int nt = 0; nt < 4; ++nt) {   // PV (VTs phys-k order matches pa)
            short8 vb0 = *(const short8*)&VTs[s][l15 + 16 * nt][quad * 8];
            short8 vb1 = *(const short8*)&VTs[s][l15 + 16 * nt][32 + quad * 8];
            floatx4 c = cacc[nt];
            c = __builtin_amdgcn_mfma_f32_16x16x32_bf16(pa0, vb0, c, 0, 0, 0);
            c = __builtin_amdgcn_mfma_f32_16x16x32_bf16(pa1, vb1, c, 0, 0, 0);
            cacc[nt] = c;
        }
    };

    for (int jt = jt0; jt <= jt1; jt += 2) {
        const int j0a = jt << 6;
        const bool has_b = (jt + 1 <= jt1);
        const int j0b = (has_b ? jt + 1 : jt1) << 6;
        __syncthreads();                        // prev reads done before overwrite
        *(uint4*)&Ks [0][krow][kc8] = kpre0;
        *(uint4*)&VTs[0][krow][kc8] = vpre0;
        *(uint4*)&Ks [1][krow][kc8] = kpre1;
        *(uint4*)&VTs[1][krow][kc8] = vpre1;
        __syncthreads();
        if (jt + 2 <= jt1) {                    // next pair's loads fly now
            const int jn0 = (jt + 2) << 6;
            const int jn1 = ((jt + 3 <= jt1) ? jt + 3 : jt1) << 6;
            kpre0 = *(const uint4*)(Kbp + (size_t)(jn0 + krow) * DE + kc8);
            vpre0 = *(const uint4*)(Vbp + (size_t)krow * T_SEQ + jn0 + kc8);
            kpre1 = *(const uint4*)(Kbp + (size_t)(jn1 + krow) * DE + kc8);
            vpre1 = *(const uint4*)(Vbp + (size_t)krow * T_SEQ + jn1 + kc8);
        }
        subtile(0, j0a);
        if (has_b) subtile(1, j0b);
    }

    // l lives per-lane for q = wave*16+l15; quads hold disjoint j-subsets
    l_acc += __shfl_xor(l_acc, 16);
    l_acc += __shfl_xor(l_acc, 32);
    const float linv = 1.0f / l_acc;
    float linv4[4];
    #pragma unroll
    for (int r = 0; r < 4; ++r) linv4[r] = __shfl(linv, quad * 4 + r);

    #pragma unroll
    for (int nt = 0; nt < 4; ++nt) {
        #pragma unroll
        for (int r = 0; r < 4; ++r) {
            int row = wave * 16 + quad * 4 + r;
            int qg = q0 + row;
            float o = cacc[nt][r] * linv4[r];
            if (qg >= sl) o = mvs[h * DE + l15 + 16 * nt] * invT;
            outbase[(size_t)row * DIM + l15 + 16 * nt] = f2bf(o);
        }
    }
}

// ============ output projection + bias + residual (LDS-staged A) ============
__global__ __launch_bounds__(256, 2) void proj_o_mfma(
    const ushort_t* __restrict__ ctx, const ushort_t* __restrict__ wb,
    const float* __restrict__ bo, const float* __restrict__ x,
    float* __restrict__ out)
{
    __shared__ __align__(16) ushort_t As[32][264];
    const int tid = threadIdx.x;
    const int wave = tid >> 6, lane = tid & 63;
    const int quad = lane >> 4, l15 = lane & 15;
    const int m0 = blockIdx.x * 32;
    const int n0 = wave * 64;
    const ushort_t* Wp = wb + (size_t)3 * 65536; // wo

    #pragma unroll
    for (int rep = 0; rep < 4; ++rep) {
        int f = rep * 256 + tid;             // 1024 uint4 = 32x256 bf16
        int row = f >> 5, c8 = (f & 31) * 8;
        *(uint4*)&As[row][c8] = *(const uint4*)(ctx + (size_t)(m0 + row) * 256 + c8);
    }

    short8 Bf[4][8];
    #pragma unroll
    for (int nt = 0; nt < 4; ++nt) {
        int nrow = n0 + nt * 16 + l15;
        #pragma unroll
        for (int ks = 0; ks < 8; ++ks)
            Bf[nt][ks] = *(const short8*)(Wp + (size_t)nrow * 256 + ks * 32 + quad * 8);
    }
    float bias4[4];
    #pragma unroll
    for (int nt = 0; nt < 4; ++nt) bias4[nt] = bo[n0 + nt * 16 + l15];

    __syncthreads();

    #pragma unroll
    for (int mb = 0; mb < 2; ++mb) {
        short8 Af[8];
        #pragma unroll
        for (int ks = 0; ks < 8; ++ks)
            Af[ks] = *(const short8*)&As[mb * 16 + l15][ks * 32 + quad * 8];
        floatx4 acc[4];
        #pragma unroll
        for (int nt = 0; nt < 4; ++nt) acc[nt] = (floatx4){0.f, 0.f, 0.f, 0.f};
        #pragma unroll
        for (int ks = 0; ks < 8; ++ks)
            #pragma unroll
            for (int nt = 0; nt < 4; ++nt)
                acc[nt] = __builtin_amdgcn_mfma_f32_16x16x32_bf16(Af[ks], Bf[nt][ks], acc[nt], 0, 0, 0);
        #pragma unroll
        for (int nt = 0; nt < 4; ++nt) {
            int d = n0 + nt * 16 + l15;
            #pragma unroll
            for (int r = 0; r < 4; ++r) {
                size_t mi = (size_t)(m0 + mb * 16 + quad * 4 + r) * 256 + d;
                out[mi] = acc[nt][r] + bias4[nt] + x[mi];
            }
        }
    }
}

extern "C" void kernel_launch(void* const* d_in, const int* in_sizes, int n_in,
                              void* d_out, int out_size, void* d_ws, size_t ws_size,
                              hipStream_t stream)
{
    (void)in_sizes; (void)n_in; (void)out_size; (void)ws_size;
    const float* x  = (const float*)d_in[0];
    const int*   sl = (const int*)d_in[1];
    const float* wq = (const float*)d_in[2];
    const float* bq = (const float*)d_in[3];
    const float* wk = (const float*)d_in[4];
    const float* bk = (const float*)d_in[5];
    const float* wv = (const float*)d_in[6];
    const float* bv = (const float*)d_in[7];
    const float* wo = (const float*)d_in[8];
    const float* bo = (const float*)d_in[9];
    const float* th = (const float*)d_in[10];
    float* out = (float*)d_out;

    char* ws = (char*)d_ws;
    const size_t SZH = (size_t)M_ROWS * DIM * sizeof(ushort_t);  // 8 MiB
    ushort_t* xb  = (ushort_t*)(ws);
    ushort_t* wb  = (ushort_t*)(ws + SZH);                       // 512 KiB
    ushort_t* Qh  = (ushort_t*)(ws + SZH + 524288);
    ushort_t* Kh  = (ushort_t*)(ws + 2*SZH + 524288);
    ushort_t* Vh  = (ushort_t*)(ws + 3*SZH + 524288);
    ushort_t* VTp = (ushort_t*)(ws + 4*SZH + 524288);
    ushort_t* Cb  = (ushort_t*)(ws + 5*SZH + 524288);
    float*    Mv  = (float*)   (ws + 6*SZH + 524288);            // 8 KiB
    float*    Thr = (float*)   (ws + 6*SZH + 524288 + 8192);     // 6 KiB (1536 f32)
    float*    Pdf = (float*)   (ws + 6*SZH + 524288 + 8192 + 6144); // 4 KiB (1024 f32)

    hipMemsetAsync(Mv, 0, NH * DE * sizeof(float), stream);
    prep_kernel<<<dim3(2186), dim3(256), 0, stream>>>(x, wq, wk, wv, wo, th, xb, wb, Thr, Pdf);
    proj_qkv_mfma<<<dim3(768), dim3(256), 0, stream>>>(xb, wb, bq, bk, bv, sl, Qh, Kh, Vh);
    vtrans_kernel<<<dim3(NH * 8), dim3(256), 0, stream>>>(Vh, VTp, Mv);
    attn_mfma_kernel<<<dim3(512), dim3(512), 0, stream>>>(Qh, Kh, VTp, Thr, Pdf, Mv, sl, Cb);
    proj_o_mfma<<<dim3(512), dim3(256), 0, stream>>>(Cb, wb, bo, x, out);
}